// Round 1
// baseline (5905.832 us; speedup 1.0000x reference)
//
#include <hip/hip_runtime.h>
#include <math.h>

namespace {

constexpr int S = 128;   // seq
constexpr int B = 128;   // batch
constexpr int E = 256;   // embed
constexpr int H = 256;   // hidden

__device__ __forceinline__ float sigmoidf(float x) { return 1.0f / (1.0f + expf(-x)); }

// ---------------- init: copy h0/c0 for the 6 recurrences ----------------
__global__ void init_state(const float* hQ, const float* cQ,
                           const float* hC, const float* cC,
                           const float* hC2, const float* cC2,
                           float* h0, float* c0) {
  int i = blockIdx.x * 256 + threadIdx.x;
  if (i >= 6 * B * H) return;
  int z = i / (B * H);
  int rem = i - z * (B * H);
  int input = z >> 1, dir = z & 1;
  const float* hs = input == 0 ? hQ : (input == 1 ? hC : hC2);
  const float* cs = input == 0 ? cQ : (input == 1 ? cC : cC2);
  h0[i] = hs[dir * B * H + rem];
  c0[i] = cs[dir * B * H + rem];
}

// ---------------- fused LSTM step ----------------
// One launch per timestep t; all 6 recurrences (3 inputs x 2 dirs).
// g = emb[tok]@Wih^T + h@Whh^T + bih + bhh   (K = 512, staged in 8 chunks of 64)
// Tile: 64 batch rows x (16 units x 4 gates); gates applied in epilogue.
// grid (16 unit-blocks, 2 row-blocks, 6 z), block 256.
__global__ __launch_bounds__(256) void lstm_step(
    const int* __restrict__ idxQ, const int* __restrict__ idxC, const int* __restrict__ idxC2,
    const float* __restrict__ emb,
    const float* __restrict__ Wih_f, const float* __restrict__ Whh_f,
    const float* __restrict__ bih_f, const float* __restrict__ bhh_f,
    const float* __restrict__ Wih_b, const float* __restrict__ Whh_b,
    const float* __restrict__ bih_b, const float* __restrict__ bhh_b,
    const float* __restrict__ hread, float* __restrict__ hwrite,
    float* __restrict__ cstate, float* __restrict__ out3, int t)
{
  const int z = blockIdx.z;
  const int input = z >> 1, dir = z & 1;
  const int u0 = blockIdx.x * 16;
  const int b0 = blockIdx.y * 64;
  const int t_eff = dir ? (S - 1 - t) : t;
  const int* idx = input == 0 ? idxQ : (input == 1 ? idxC : idxC2);
  const float* Wih = dir ? Wih_b : Wih_f;
  const float* Whh = dir ? Whh_b : Whh_f;
  const float* bih = dir ? bih_b : bih_f;
  const float* bhh = dir ? bhh_b : bhh_f;

  __shared__ float Al[64][68];  // 64 batch rows x 64 k (pad 68: b128-aligned, low conflicts)
  __shared__ float Wl[64][68];  // 64 gate-cols  x 64 k
  __shared__ int tok[64];

  const int tid = threadIdx.x;
  if (tid < 64) tok[tid] = idx[t_eff * B + b0 + tid];

  const int uu = tid & 15;   // unit within block
  const int rg = tid >> 4;   // row group 0..15 (rows rg*4..rg*4+3)
  const int u = u0 + uu;

  float acc[4][4];  // [ri][gate]
#pragma unroll
  for (int ri = 0; ri < 4; ++ri)
#pragma unroll
    for (int g = 0; g < 4; ++g)
      acc[ri][g] = bih[g * 256 + u] + bhh[g * 256 + u];

  for (int kc = 0; kc < 8; ++kc) {
    __syncthreads();
    if (kc < 4) {  // x-part: gather embedding rows
      const int kb = kc * 64;
#pragma unroll
      for (int i = 0; i < 16; ++i) {
        int e = i * 256 + tid;
        int kk = e & 63, r = e >> 6;
        Al[r][kk] = emb[(long)tok[r] * E + kb + kk];
      }
    } else {       // h-part
      const int kb = (kc - 4) * 64;
      const float* hs = hread + ((long)z * B + b0) * H + kb;
#pragma unroll
      for (int i = 0; i < 16; ++i) {
        int e = i * 256 + tid;
        int kk = e & 63, r = e >> 6;
        Al[r][kk] = hs[r * H + kk];
      }
    }
    {
      const float* Wsrc = (kc < 4) ? Wih : Whh;
      const int kb = (kc & 3) * 64;
#pragma unroll
      for (int i = 0; i < 16; ++i) {
        int e = i * 256 + tid;
        int kk = e & 63, c = e >> 6;                   // c = gate*16 + unit
        int gcol = (c >> 4) * 256 + u0 + (c & 15);
        Wl[c][kk] = Wsrc[(long)gcol * H + kb + kk];
      }
    }
    __syncthreads();
#pragma unroll
    for (int k4 = 0; k4 < 64; k4 += 4) {
      float4 a[4], w[4];
#pragma unroll
      for (int ri = 0; ri < 4; ++ri) a[ri] = *(const float4*)&Al[rg * 4 + ri][k4];
#pragma unroll
      for (int g = 0; g < 4; ++g) w[g] = *(const float4*)&Wl[g * 16 + uu][k4];
#pragma unroll
      for (int ri = 0; ri < 4; ++ri)
#pragma unroll
        for (int g = 0; g < 4; ++g)
          acc[ri][g] += a[ri].x * w[g].x + a[ri].y * w[g].y
                      + a[ri].z * w[g].z + a[ri].w * w[g].w;
    }
  }

  // epilogue: torch gate order i,f,g,o
  float* cs = cstate + (long)z * B * H;
  float* hw = hwrite + (long)z * B * H;
  float* op = out3 + (long)input * B * S * 2 * H;
#pragma unroll
  for (int ri = 0; ri < 4; ++ri) {
    int b = b0 + rg * 4 + ri;
    float ig = sigmoidf(acc[ri][0]);
    float fg = sigmoidf(acc[ri][1]);
    float gg = tanhf(acc[ri][2]);
    float og = sigmoidf(acc[ri][3]);
    float cn = fg * cs[b * H + u] + ig * gg;
    float hn = og * tanhf(cn);
    cs[b * H + u] = cn;
    hw[b * H + u] = hn;
    op[((long)b * S + t_eff) * (2 * H) + dir * H + u] = hn;
  }
}

// ---------------- generic fp32 GEMM, C = act(A@B^T + bias) ----------------
// A: MxK (lda), B: NxK (ldb), C: MxN (ldc). 64x64 tile, K % 64 == 0.
// grid (N/64, M/64, batch), block 256.
template <bool TANH>
__global__ __launch_bounds__(256) void gemm_nt(
    const float* __restrict__ A, const float* __restrict__ B_,
    const float* __restrict__ bias, float* __restrict__ C,
    int lda, int ldb, int ldc, int K, long sA, long sB, long sC)
{
  A += blockIdx.z * sA; B_ += blockIdx.z * sB; C += blockIdx.z * sC;
  const int n0 = blockIdx.x * 64, m0 = blockIdx.y * 64;
  __shared__ float Al[64][68], Bl[64][68];
  const int tid = threadIdx.x, uu = tid & 15, rg = tid >> 4;
  float acc[4][4] = {};
  for (int kb = 0; kb < K; kb += 64) {
    __syncthreads();
#pragma unroll
    for (int i = 0; i < 16; ++i) {
      int e = i * 256 + tid;
      int kk = e & 63, r = e >> 6;
      Al[r][kk] = A[(long)(m0 + r) * lda + kb + kk];
      Bl[r][kk] = B_[(long)(n0 + r) * ldb + kb + kk];
    }
    __syncthreads();
#pragma unroll
    for (int k4 = 0; k4 < 64; k4 += 4) {
      float4 a[4], w[4];
#pragma unroll
      for (int ri = 0; ri < 4; ++ri) a[ri] = *(const float4*)&Al[rg * 4 + ri][k4];
#pragma unroll
      for (int ci = 0; ci < 4; ++ci) w[ci] = *(const float4*)&Bl[ci * 16 + uu][k4];
#pragma unroll
      for (int ri = 0; ri < 4; ++ri)
#pragma unroll
        for (int ci = 0; ci < 4; ++ci)
          acc[ri][ci] += a[ri].x * w[ci].x + a[ri].y * w[ci].y
                       + a[ri].z * w[ci].z + a[ri].w * w[ci].w;
    }
  }
#pragma unroll
  for (int ri = 0; ri < 4; ++ri) {
    int m = m0 + rg * 4 + ri;
#pragma unroll
    for (int ci = 0; ci < 4; ++ci) {
      int n = n0 + ci * 16 + uu;
      float v = acc[ri][ci];
      if (bias) v += bias[n];
      if (TANH) v = tanhf(v);
      C[(long)m * ldc + n] = v;
    }
  }
}

// ---------------- generic fp32 GEMM, C = A@B (B row-major KxN) ----------------
// grid (N/64, M/64, batch), block 256. K % 64 == 0.
__global__ __launch_bounds__(256) void gemm_nn(
    const float* __restrict__ A, const float* __restrict__ B_,
    float* __restrict__ C,
    int lda, int ldb, int ldc, int K, long sA, long sB, long sC)
{
  A += blockIdx.z * sA; B_ += blockIdx.z * sB; C += blockIdx.z * sC;
  const int n0 = blockIdx.x * 64, m0 = blockIdx.y * 64;
  __shared__ float Al[64][68];   // [row][k]
  __shared__ float Bl[64][68];   // [k][col]
  const int tid = threadIdx.x, uu = tid & 15, rg = tid >> 4;
  float acc[4][4] = {};  // [ri][ci], cols n0 + uu*4 + ci
  for (int kb = 0; kb < K; kb += 64) {
    __syncthreads();
#pragma unroll
    for (int i = 0; i < 16; ++i) {
      int e = i * 256 + tid;
      int kk = e & 63, r = e >> 6;
      Al[r][kk] = A[(long)(m0 + r) * lda + kb + kk];
      Bl[r][kk] = B_[(long)(kb + r) * ldb + n0 + kk];  // r is k-index, kk is col
    }
    __syncthreads();
#pragma unroll
    for (int kk = 0; kk < 64; ++kk) {
      float4 w = *(const float4*)&Bl[kk][uu * 4];
      float a0 = Al[rg * 4 + 0][kk], a1 = Al[rg * 4 + 1][kk];
      float a2 = Al[rg * 4 + 2][kk], a3 = Al[rg * 4 + 3][kk];
      acc[0][0] += a0 * w.x; acc[0][1] += a0 * w.y; acc[0][2] += a0 * w.z; acc[0][3] += a0 * w.w;
      acc[1][0] += a1 * w.x; acc[1][1] += a1 * w.y; acc[1][2] += a1 * w.z; acc[1][3] += a1 * w.w;
      acc[2][0] += a2 * w.x; acc[2][1] += a2 * w.y; acc[2][2] += a2 * w.z; acc[2][3] += a2 * w.w;
      acc[3][0] += a3 * w.x; acc[3][1] += a3 * w.y; acc[3][2] += a3 * w.z; acc[3][3] += a3 * w.w;
    }
  }
#pragma unroll
  for (int ri = 0; ri < 4; ++ri) {
    int m = m0 + rg * 4 + ri;
    float4 v = make_float4(acc[ri][0], acc[ri][1], acc[ri][2], acc[ri][3]);
    *(float4*)&C[(long)m * ldc + n0 + uu * 4] = v;
  }
}

// ---------------- softmax over last axis of Hm[b][s][t] -> A same layout ----------------
__global__ void softmax_row(const float* __restrict__ Hm, float* __restrict__ A) {
  const int row = blockIdx.x;          // b*S + s
  const float* p = Hm + (long)row * S;
  const int l = threadIdx.x;
  float v0 = p[l], v1 = p[l + 64];
  float m = fmaxf(v0, v1);
#pragma unroll
  for (int o = 32; o > 0; o >>= 1) m = fmaxf(m, __shfl_xor(m, o));
  float e0 = expf(v0 - m), e1 = expf(v1 - m);
  float s = e0 + e1;
#pragma unroll
  for (int o = 32; o > 0; o >>= 1) s += __shfl_xor(s, o);
  float inv = 1.0f / s;
  float* q = A + (long)row * S;
  q[l] = e0 * inv; q[l + 64] = e1 * inv;
}

// softmax over FIRST (row) axis of Hm for fixed column, written TRANSPOSED:
// A[b][col][t] = exp(Hm[b][t][col]) / sum_t  -> MC becomes a plain NN GEMM.
__global__ void softmax_colT(const float* __restrict__ Hm, float* __restrict__ A) {
  const int b = blockIdx.x >> 7;
  const int col = blockIdx.x & 127;
  const float* p = Hm + (long)b * S * S + col;
  const int l = threadIdx.x;
  float v0 = p[(long)l * S], v1 = p[(long)(l + 64) * S];
  float m = fmaxf(v0, v1);
#pragma unroll
  for (int o = 32; o > 0; o >>= 1) m = fmaxf(m, __shfl_xor(m, o));
  float e0 = expf(v0 - m), e1 = expf(v1 - m);
  float s = e0 + e1;
#pragma unroll
  for (int o = 32; o > 0; o >>= 1) s += __shfl_xor(s, o);
  float inv = 1.0f / s;
  float* q = A + ((long)b * S + col) * S;
  q[l] = e0 * inv; q[l + 64] = e1 * inv;
}

}  // namespace

extern "C" void kernel_launch(void* const* d_in, const int* in_sizes, int n_in,
                              void* d_out, int out_size, void* d_ws, size_t ws_size,
                              hipStream_t stream) {
  const int* idxQ    = (const int*)d_in[1];
  const int* idxC    = (const int*)d_in[2];
  const int* idxC2   = (const int*)d_in[3];
  const float* hQ    = (const float*)d_in[4];
  const float* cQ    = (const float*)d_in[5];
  const float* hC    = (const float*)d_in[6];
  const float* cC    = (const float*)d_in[7];
  const float* hC2   = (const float*)d_in[8];
  const float* cC2   = (const float*)d_in[9];
  const float* emb   = (const float*)d_in[10];
  const float* Wih_f = (const float*)d_in[11];
  const float* Whh_f = (const float*)d_in[12];
  const float* bih_f = (const float*)d_in[13];
  const float* bhh_f = (const float*)d_in[14];
  const float* Wih_b = (const float*)d_in[15];
  const float* Whh_b = (const float*)d_in[16];
  const float* bih_b = (const float*)d_in[17];
  const float* bhh_b = (const float*)d_in[18];
  const float* S1W   = (const float*)d_in[19];
  const float* S1b   = (const float*)d_in[20];
  float* out = (float*)d_out;

  // workspace layout (floats); total = 38,338,560 floats = 153.4 MB
  const long OUT1 = (long)B * S * 2 * H;      // 8,388,608
  const long ST   = (long)6 * B * H;          // 196,608
  float* ws    = (float*)d_ws;
  float* out3  = ws;                // 3 * OUT1
  float* hbuf0 = out3 + 3 * OUT1;   // ST   (h double-buffered: inter-block race avoidance)
  float* hbuf1 = hbuf0 + ST;        // ST
  float* cbuf  = hbuf1 + ST;        // ST
  float* Ct    = cbuf + ST;         // OUT1
  float* Hm    = Ct + OUT1;         // B*S*S = 2,097,152
  float* Ab    = Hm + (long)B * S * S;  // 2,097,152

  init_state<<<(6 * B * H + 255) / 256, 256, 0, stream>>>(hQ, cQ, hC, cC, hC2, cC2, hbuf0, cbuf);

  for (int t = 0; t < S; ++t) {
    float* hr = (t & 1) ? hbuf1 : hbuf0;
    float* hw = (t & 1) ? hbuf0 : hbuf1;
    lstm_step<<<dim3(16, 2, 6), 256, 0, stream>>>(
        idxQ, idxC, idxC2, emb,
        Wih_f, Whh_f, bih_f, bhh_f, Wih_b, Whh_b, bih_b, bhh_b,
        hr, hw, cbuf, out3, t);
  }

  // attention x2: (out_q, out_c) and (out_q, out_c2)
  for (int p = 0; p < 2; ++p) {
    const float* Q  = out3;
    const float* C0 = out3 + (long)(1 + p) * OUT1;
    // Ct = tanh(C0 @ S1W^T + S1b):  M=16384, N=512, K=512
    gemm_nt<true><<<dim3(8, 256, 1), 256, 0, stream>>>(
        C0, S1W, S1b, Ct, 512, 512, 512, 512, 0, 0, 0);
    // Hm[b] = Q[b] @ Ct[b]^T:  per-batch M=N=128, K=512
    gemm_nt<false><<<dim3(2, 2, B), 256, 0, stream>>>(
        Q, Ct, nullptr, Hm, 512, 512, 128, 512,
        (long)S * 512, (long)S * 512, (long)S * S);
    // AQ = softmax(Hm, axis=-1)
    softmax_row<<<B * S, 64, 0, stream>>>(Hm, Ab);
    // MQ[b] = AQ[b] @ Q[b]:  M=128, N=512, K=128
    float* MQ = out + (long)(2 * p) * OUT1;
    gemm_nn<<<dim3(8, 2, B), 256, 0, stream>>>(
        Ab, Q, MQ, 128, 512, 512, 128,
        (long)S * S, (long)S * 512, (long)S * 512);
    // ACt[b][s][t] = column-softmax of Hm (normalized over first axis), transposed
    softmax_colT<<<B * S, 64, 0, stream>>>(Hm, Ab);
    // MC[b] = ACt[b] @ MQ[b]
    float* MC = out + (long)(2 * p + 1) * OUT1;
    gemm_nn<<<dim3(8, 2, B), 256, 0, stream>>>(
        Ab, MQ, MC, 128, 512, 512, 128,
        (long)S * S, (long)S * 512, (long)S * 512);
  }
}